// Round 5
// baseline (846.122 us; speedup 1.0000x reference)
//
#include <hip/hip_runtime.h>

// Brute N^2 neighborlist (upper-triangular pairs), N=6000, P=17,997,000.
// Output layout (flat f32): [0,P) i | [P,2P) j | [2P,3P) d | [3P,6P) r_xyz.
//
// R5 = R4 with the compile fix: __builtin_nontemporal_store requires a
// native clang vector type, not HIP_vector_type -> use ext_vector_type(4).
// Non-temporal float4 stores for the entire 432 MB output stream (never
// re-read; nt avoids L2 dirty-line retention/eviction overhead).
// 8 pairs/thread amortizes the triangular inversion; no LDS (R3 showed the
// store lane-pattern is irrelevant). PBC wrap replicates numpy remainder
// bitwise (Sterbenz-exact branches, |r| < box, box > 0); explicit _rn
// intrinsics forbid contraction so the d<=0.5 mask cannot flip vs numpy.

constexpr int NPART  = 6000;
constexpr int NPAIRS = 17997000;     // N*(N-1)/2; divisible by 8
constexpr float CUT  = 0.5f;
constexpr int TPB = 256;
constexpr int PPT = 8;               // pairs per thread

typedef float v4f __attribute__((ext_vector_type(4)));

__device__ __forceinline__ int row_start(int i) {
    // pairs before row i: S(i) = i*(N-1) - i*(i-1)/2  (fits int32)
    return i * (NPART - 1) - (i * (i - 1)) / 2;
}

// numpy remainder(r+h, b) - h for |r| < b, b > 0, h = b/2 — bitwise-exact.
__device__ __forceinline__ float pbc_wrap(float r, float b, float h) {
    float v = __fadd_rn(r, h);
    if (v >= b)       v = __fsub_rn(v, b);
    else if (v < 0.f) v = __fadd_rn(v, b);
    return __fsub_rn(v, h);
}

__device__ __forceinline__ void nt_store4(float* a, float x, float y, float z, float w) {
    v4f v = {x, y, z, w};
    __builtin_nontemporal_store(v, (v4f*)a);
}

__global__ __launch_bounds__(TPB) void nbl_kernel(
    const float* __restrict__ pos,     // [N,3]
    const float* __restrict__ boxv,    // [3,3]
    const int*  __restrict__ is_per,
    float* __restrict__ out)
{
    const int p = (blockIdx.x * TPB + threadIdx.x) * PPT;
    if (p >= NPAIRS) return;           // NPAIRS % PPT == 0: no partial threads

    // invert triangular index (fp32 estimate + int fixup)
    const float A = 2.0f * NPART - 1.0f;   // 11999
    float disc = A * A - 8.0f * (float)p;
    int i = (int)((A - sqrtf(disc)) * 0.5f);
    if (i < 0) i = 0;
    if (i > NPART - 2) i = NPART - 2;
    while (i < NPART - 2 && row_start(i + 1) <= p) ++i;
    while (i > 0 && row_start(i) > p) --i;
    int j = i + 1 + (p - row_start(i));

    const bool per = (*is_per != 0);
    const float bx = boxv[0], by = boxv[4], bz = boxv[8];
    const float hx = __fmul_rn(bx, 0.5f);
    const float hy = __fmul_rn(by, 0.5f);
    const float hz = __fmul_rn(bz, 0.5f);

    float xi = pos[3 * i + 0], yi = pos[3 * i + 1], zi = pos[3 * i + 2];

    float oi[PPT], oj[PPT], od[PPT], orr[3 * PPT];

    #pragma unroll
    for (int k = 0; k < PPT; ++k) {
        float xj = pos[3 * j + 0], yj = pos[3 * j + 1], zj = pos[3 * j + 2];
        float rx = __fsub_rn(xi, xj);
        float ry = __fsub_rn(yi, yj);
        float rz = __fsub_rn(zi, zj);
        if (per) {
            rx = pbc_wrap(rx, bx, hx);
            ry = pbc_wrap(ry, by, hy);
            rz = pbc_wrap(rz, bz, hz);
        }
        float s = __fadd_rn(__fadd_rn(__fmul_rn(rx, rx), __fmul_rn(ry, ry)),
                            __fmul_rn(rz, rz));
        float d = __fsqrt_rn(s);
        bool in = (d <= CUT);

        oi[k] = in ? (float)i : -1.0f;
        oj[k] = in ? (float)j : -1.0f;
        od[k] = in ? d : 0.0f;
        orr[3 * k + 0] = in ? rx : 0.0f;
        orr[3 * k + 1] = in ? ry : 0.0f;
        orr[3 * k + 2] = in ? rz : 0.0f;

        // advance to next upper-triangular pair
        ++j;
        if (j == NPART) { ++i; j = i + 1;
            xi = pos[3 * i + 0]; yi = pos[3 * i + 1]; zi = pos[3 * i + 2]; }
    }

    // i / j / d streams: 2 nt float4 each (p % 8 == 0 -> 16B aligned)
    #pragma unroll
    for (int s = 0; s < PPT / 4; ++s) {
        nt_store4(out + p + 4 * s,
                  oi[4 * s], oi[4 * s + 1], oi[4 * s + 2], oi[4 * s + 3]);
        nt_store4(out + NPAIRS + p + 4 * s,
                  oj[4 * s], oj[4 * s + 1], oj[4 * s + 2], oj[4 * s + 3]);
        nt_store4(out + 2 * NPAIRS + p + 4 * s,
                  od[4 * s], od[4 * s + 1], od[4 * s + 2], od[4 * s + 3]);
    }
    // r stream: 24 floats/thread, contiguous, 3*p % 4 == 0 -> 6 nt float4
    float* rb = out + 3 * NPAIRS + 3 * p;
    #pragma unroll
    for (int s = 0; s < (3 * PPT) / 4; ++s) {
        nt_store4(rb + 4 * s,
                  orr[4 * s], orr[4 * s + 1], orr[4 * s + 2], orr[4 * s + 3]);
    }
}

extern "C" void kernel_launch(void* const* d_in, const int* in_sizes, int n_in,
                              void* d_out, int out_size, void* d_ws, size_t ws_size,
                              hipStream_t stream) {
    const float* pos    = (const float*)d_in[0];
    const float* boxv   = (const float*)d_in[1];
    const int*   is_per = (const int*)d_in[2];
    float* out = (float*)d_out;

    const int nthreads = NPAIRS / PPT;                 // 2,249,625
    const int grid = (nthreads + TPB - 1) / TPB;       // 8,789
    nbl_kernel<<<grid, TPB, 0, stream>>>(pos, boxv, is_per, out);
}

// Round 6
// 440.876 us; speedup vs baseline: 1.9192x; 1.9192x over previous
//
#include <hip/hip_runtime.h>

// Brute N^2 neighborlist (upper-triangular pairs), N=6000, P=17,997,000.
// Output layout (flat f32): [0,P) i | [P,2P) j | [2P,3P) d | [3P,6P) r_xyz.
//
// R6: revert nt stores (R5: nt bypassed L2 write-combining -> 2.6x HBM write
// amplification on the strided r-stream, 515 us). Back to write-back float4
// stores with LDS-staged r (every store instruction wave-contiguous).
// New: exact int32 discriminant for the triangular inversion — the fp32
// A*A-8p cancels catastrophically near p=NPAIRS and can go negative ->
// sqrtf=NaN -> i=0 -> ~6000-iteration fixup loop on the last waves (tail).
// int32 disc = 143976001-8p >= 9 always; fixup converges in <=2 steps.
// 8 pairs/thread halves inversion work. PBC wrap replicates numpy remainder
// bitwise (Sterbenz-exact branches, |r| < box, box > 0); explicit _rn
// intrinsics forbid contraction so the d<=0.5 mask cannot flip vs numpy.

constexpr int NPART  = 6000;
constexpr int NPAIRS = 17997000;     // N*(N-1)/2; divisible by 8
constexpr float CUT  = 0.5f;
constexpr int TPB = 256;
constexpr int PPT = 8;               // pairs per thread
constexpr int PPB = TPB * PPT;       // 2048 pairs per block

__device__ __forceinline__ int row_start(int i) {
    // pairs before row i: S(i) = i*(N-1) - i*(i-1)/2  (fits int32)
    return i * (NPART - 1) - (i * (i - 1)) / 2;
}

// numpy remainder(r+h, b) - h for |r| < b, b > 0, h = b/2 — bitwise-exact.
__device__ __forceinline__ float pbc_wrap(float r, float b, float h) {
    float v = __fadd_rn(r, h);
    if (v >= b)       v = __fsub_rn(v, b);
    else if (v < 0.f) v = __fadd_rn(v, b);
    return __fsub_rn(v, h);
}

__global__ __launch_bounds__(TPB) void nbl_kernel(
    const float* __restrict__ pos,     // [N,3]
    const float* __restrict__ boxv,    // [3,3]
    const int*  __restrict__ is_per,
    float* __restrict__ out)
{
    __shared__ float lds_r[PPB * 3];   // 24,576 B: r-triples in final layout

    const int t     = threadIdx.x;
    const int pbase = blockIdx.x * PPB;
    const int p     = pbase + t * PPT;
    // pairs in this block: 2048, or 1224 for the last block (both % 8 == 0,
    // so each thread's 8 pairs are entirely valid or entirely invalid).
    const int nvalid = (NPAIRS - pbase < PPB) ? (NPAIRS - pbase) : PPB;

    if (t * PPT < nvalid) {
        // invert triangular index: exact int32 discriminant, fp32 sqrt
        // disc = (2N-1)^2 - 8p = 143976001 - 8p, in [9, 143976001]
        int disc_i = 143976001 - 8 * p;
        float sq = sqrtf((float)disc_i);          // abs err tiny; i off by <=1
        int i = (int)((11999.0f - sq) * 0.5f);
        if (i < 0) i = 0;
        if (i > NPART - 2) i = NPART - 2;
        while (i < NPART - 2 && row_start(i + 1) <= p) ++i;
        while (i > 0 && row_start(i) > p) --i;
        int j = i + 1 + (p - row_start(i));

        const bool per = (*is_per != 0);
        const float bx = boxv[0], by = boxv[4], bz = boxv[8];
        const float hx = __fmul_rn(bx, 0.5f);
        const float hy = __fmul_rn(by, 0.5f);
        const float hz = __fmul_rn(bz, 0.5f);

        float xi = pos[3 * i + 0], yi = pos[3 * i + 1], zi = pos[3 * i + 2];

        float oi[PPT], oj[PPT], od[PPT], orr[3 * PPT];

        #pragma unroll
        for (int k = 0; k < PPT; ++k) {
            float xj = pos[3 * j + 0], yj = pos[3 * j + 1], zj = pos[3 * j + 2];
            float rx = __fsub_rn(xi, xj);
            float ry = __fsub_rn(yi, yj);
            float rz = __fsub_rn(zi, zj);
            if (per) {
                rx = pbc_wrap(rx, bx, hx);
                ry = pbc_wrap(ry, by, hy);
                rz = pbc_wrap(rz, bz, hz);
            }
            float s = __fadd_rn(__fadd_rn(__fmul_rn(rx, rx), __fmul_rn(ry, ry)),
                                __fmul_rn(rz, rz));
            float d = __fsqrt_rn(s);
            bool in = (d <= CUT);

            oi[k] = in ? (float)i : -1.0f;
            oj[k] = in ? (float)j : -1.0f;
            od[k] = in ? d : 0.0f;
            orr[3 * k + 0] = in ? rx : 0.0f;
            orr[3 * k + 1] = in ? ry : 0.0f;
            orr[3 * k + 2] = in ? rz : 0.0f;

            // advance to next upper-triangular pair
            ++j;
            if (j == NPART) { ++i; j = i + 1;
                xi = pos[3 * i + 0]; yi = pos[3 * i + 1]; zi = pos[3 * i + 2]; }
        }

        // stage r-triples in LDS in final layout (16B-aligned b128 writes)
        float4* lv = (float4*)(lds_r + 3 * PPT * t);
        #pragma unroll
        for (int s = 0; s < (3 * PPT) / 4; ++s)
            lv[s] = make_float4(orr[4 * s], orr[4 * s + 1],
                                orr[4 * s + 2], orr[4 * s + 3]);

        // i / j / d streams: wave-contiguous float4 (p % 8 == 0)
        #pragma unroll
        for (int s = 0; s < PPT / 4; ++s) {
            *(float4*)(out + p + 4 * s) =
                make_float4(oi[4 * s], oi[4 * s + 1], oi[4 * s + 2], oi[4 * s + 3]);
            *(float4*)(out + NPAIRS + p + 4 * s) =
                make_float4(oj[4 * s], oj[4 * s + 1], oj[4 * s + 2], oj[4 * s + 3]);
            *(float4*)(out + 2 * NPAIRS + p + 4 * s) =
                make_float4(od[4 * s], od[4 * s + 1], od[4 * s + 2], od[4 * s + 3]);
        }
    }

    __syncthreads();

    // stream r out lane-contiguously: block owns floats [3*pbase, 3*pbase+3*nvalid)
    // 3*pbase % 4 == 0, 3*nvalid % 4 == 0 -> exact float4 granularity.
    const int nf4 = (3 * nvalid) / 4;                 // 1536 or 918
    float4* rdst = (float4*)(out + 3 * NPAIRS + 3 * pbase);
    const float4* rsrc = (const float4*)lds_r;
    #pragma unroll
    for (int s = 0; s < 6; ++s) {
        int q = t + TPB * s;
        if (q < nf4) rdst[q] = rsrc[q];
    }
}

extern "C" void kernel_launch(void* const* d_in, const int* in_sizes, int n_in,
                              void* d_out, int out_size, void* d_ws, size_t ws_size,
                              hipStream_t stream) {
    const float* pos    = (const float*)d_in[0];
    const float* boxv   = (const float*)d_in[1];
    const int*   is_per = (const int*)d_in[2];
    float* out = (float*)d_out;

    const int grid = (NPAIRS + PPB - 1) / PPB;   // 8,788
    nbl_kernel<<<grid, TPB, 0, stream>>>(pos, boxv, is_per, out);
}